// Round 2
// baseline (143.133 us; speedup 1.0000x reference)
//
#include <hip/hip_runtime.h>
#include <hip/hip_bf16.h>
#include <stdint.h>

#define T_DIM 1024
#define B_DIM 8

typedef __attribute__((ext_vector_type(8))) short short8;
typedef __attribute__((ext_vector_type(4))) float f32x4;

__device__ inline void gll16(const void* g, void* l) {
  __builtin_amdgcn_global_load_lds((__attribute__((address_space(1))) void*)g,
                                   (__attribute__((address_space(3))) void*)l,
                                   16, 0, 0);
}

// ---------------- fp32 -> bf16 convert ----------------
__global__ __launch_bounds__(256) void convert_kernel(const float* __restrict__ F,
                                                      __hip_bfloat16* __restrict__ Fb) {
  const int t = blockIdx.x * 256 + threadIdx.x;
  const float4 v = ((const float4*)F)[t];
  union { __hip_bfloat16 h[4]; uint64_t u; } p;
  p.h[0] = __float2bfloat16(v.x);
  p.h[1] = __float2bfloat16(v.y);
  p.h[2] = __float2bfloat16(v.z);
  p.h[3] = __float2bfloat16(v.w);
  ((uint64_t*)Fb)[t] = p.u;
}

// ---------------- fused Gram + row-partial kernel ----------------
// 512 threads = 8 waves (2x4 wave grid) on a 128x128 tile.
// Round-2 change: counted-vmcnt pipeline (T4). Per K-step:
//   vmcnt(4) -> barrier A -> ds_read frags->regs -> lgkmcnt(0) ->
//   barrier B -> stage(t+2) into just-freed buffer -> MFMA (setprio 1).
// __syncthreads (vmcnt(0) drain) is GONE from the main loop, so next-tile
// global_load_lds stay in flight across barriers (m218 mechanism).
// B is staged unconditionally (diag tiles too) so the in-flight count is a
// uniform literal 4. Mask loads are issued before the prologue stages so the
// compiler's wait on them (vmcnt(8)) leaves the stage loads flying.
__global__ __launch_bounds__(512, 4) void fused_kernel(const __hip_bfloat16* __restrict__ Fb,
                                                       const float* __restrict__ M,
                                                       const int* __restrict__ icl,
                                                       float* __restrict__ part) {
  const int id = blockIdx.x;
  const int b  = id & 7;          // XCD = wgid % 8 -> all tiles of batch b on one XCD
  const int rt = (id >> 3) & 7;
  const int ct = id >> 6;
  const int L  = icl[b] + 1;
  if (rt * 128 >= L || ct * 128 >= L) return;   // tile fully invalid (uniform exit)

  __shared__ char smem[65536];
  __hip_bfloat16* As = (__hip_bfloat16*)smem;            // [2 buf][2 kk][128][32] = 32 KB
  __hip_bfloat16* Bs = (__hip_bfloat16*)(smem + 32768);  // 32 KB
  float* rp = (float*)smem;  // reused after K-loop: 5 arrays of 128x4 floats
  float* rp_m = rp;          // [row*4 + slot]
  float* rp_d = rp + 512;
  float* rp_s = rp + 1024;
  float* rp_c = rp + 1536;
  float* rp_b = rp + 2048;

  const __hip_bfloat16* F = Fb + ((size_t)b << 20);
  const int tid  = threadIdx.x;
  const int lane = tid & 63;
  const int wave = tid >> 6;            // 0..7
  const int wrow = (wave >> 2) * 64;    // 0 / 64
  const int wcol = (wave & 3) * 32;     // 0 / 32 / 64 / 96
  const int row0 = rt * 128;
  const int col0 = ct * 128;

  const int fr = lane & 15;             // fragment row/col within 16
  const int q  = lane >> 4;             // quarter-wave (k-granule wanted)
  const int sl8 = (q ^ ((fr >> 1) & 3)) * 8;   // swizzled slot (elements)

  // staging: thread l -> LDS row l>>2, slot l&3; source granule = swizzle^-1
  const int srow = tid >> 2;                                  // 0..127
  const int sgk  = (((tid & 3) ^ ((tid >> 3) & 3)) * 8);      // source k offset

  const int gc0 = col0 + wcol + fr;
  const int gc1 = gc0 + 16;

  // ---- mask loads issued first (oldest VMEM, complete during prologue) ----
  float mv0[16], mv1[16];               // [ti*4+r], compile-time indexed
  {
    const float* Mb = M + ((size_t)b << 20);
#pragma unroll
    for (int ti = 0; ti < 4; ti++)
#pragma unroll
      for (int r = 0; r < 4; r++) {
        const int grow = row0 + wrow + ti * 16 + q * 4 + r;
        const float* mrow = Mb + ((size_t)grow << 10);
        mv0[ti * 4 + r] = (gc0 < L) ? mrow[gc0] : 0.f;
        mv1[ti * 4 + r] = (gc1 < L) ? mrow[gc1] : 0.f;
      }
  }

  const size_t arow = (size_t)(row0 + srow) * T_DIM + sgk;
  const size_t brow = (size_t)(col0 + srow) * T_DIM + sgk;

  auto stage = [&](int buf, int step) {
    const int kb = step << 6;     // BK = 64
#pragma unroll
    for (int p = 0; p < 2; p++)
      gll16(F + arow + kb + p * 32, As + buf * 8192 + p * 4096 + tid * 8);
#pragma unroll
    for (int p = 0; p < 2; p++)
      gll16(F + brow + kb + p * 32, Bs + buf * 8192 + p * 4096 + tid * 8);
  };

  // prologue: two tiles in flight (8 gll16)
  stage(0, 0);
  stage(1, 1);

  // pack mask bits (compiler waits mask loads w/ vmcnt(8): stages keep flying)
  // bit index: ti*8 + r*2 + j  (j=0 -> gc0 column, j=1 -> gc1 column)
  uint32_t mbits = 0;
#pragma unroll
  for (int ti = 0; ti < 4; ti++)
#pragma unroll
    for (int r = 0; r < 4; r++) {
      const uint32_t b0 = (mv0[ti * 4 + r] != 0.f) ? 1u : 0u;
      const uint32_t b1 = (mv1[ti * 4 + r] != 0.f) ? 1u : 0u;
      mbits |= (b0 << (ti * 8 + r * 2)) | (b1 << (ti * 8 + r * 2 + 1));
    }

  f32x4 acc[4][2];
#pragma unroll
  for (int i = 0; i < 4; i++)
#pragma unroll
    for (int j = 0; j < 2; j++) acc[i][j] = (f32x4){0.f, 0.f, 0.f, 0.f};

#pragma unroll
  for (int t = 0; t < 16; ++t) {
    const int cur = t & 1;
    // own tile-t loads landed; tile-(t+1) loads (4) stay in flight
    if (t < 15) { asm volatile("s_waitcnt vmcnt(4)" ::: "memory"); }
    else        { asm volatile("s_waitcnt vmcnt(0)" ::: "memory"); }
    __builtin_amdgcn_s_barrier();                 // (A) tile t visible everywhere
    __builtin_amdgcn_sched_barrier(0);

    short8 af[2][4], bfr[2][2];
    const __hip_bfloat16* Ab = As + cur * 8192;
    const __hip_bfloat16* Bb = Bs + cur * 8192;
#pragma unroll
    for (int kk = 0; kk < 2; kk++) {
#pragma unroll
      for (int tt = 0; tt < 4; tt++)
        af[kk][tt] = *(const short8*)(Ab + kk * 4096 + (wrow + tt * 16 + fr) * 32 + sl8);
#pragma unroll
      for (int j = 0; j < 2; j++)
        bfr[kk][j] = *(const short8*)(Bb + kk * 4096 + (wcol + j * 16 + fr) * 32 + sl8);
    }
    asm volatile("s_waitcnt lgkmcnt(0)" ::: "memory");
    __builtin_amdgcn_sched_barrier(0);
    __builtin_amdgcn_s_barrier();                 // (B) all reads done -> buf free
    __builtin_amdgcn_sched_barrier(0);

    if (t < 14) stage(cur, t + 2);                // refill freed buffer

    __builtin_amdgcn_s_setprio(1);
#pragma unroll
    for (int kk = 0; kk < 2; kk++)
#pragma unroll
      for (int ti = 0; ti < 4; ti++)
#pragma unroll
        for (int tj = 0; tj < 2; tj++)
          acc[ti][tj] = __builtin_amdgcn_mfma_f32_16x16x32_bf16(af[kk][ti], bfr[kk][tj], acc[ti][tj], 0, 0, 0);
    __builtin_amdgcn_s_setprio(0);
  }
  __syncthreads();   // all frag reads done before rp aliases the staging LDS

  // ---- epilogue ----
  // C/D layout: col = lane&15, row = (lane>>4)*4 + r  [m89-verified]
#pragma unroll
  for (int ti = 0; ti < 4; ti++) {
#pragma unroll
    for (int r = 0; r < 4; r++) {
      const int lrow = wrow + ti * 16 + q * 4 + r;    // 0..127
      const int grow = row0 + lrow;
      const float mk0 = (float)((mbits >> (ti * 8 + r * 2)) & 1u);
      const float mk1 = (float)((mbits >> (ti * 8 + r * 2 + 1)) & 1u);
      const float s0 = (gc0 < L) ? acc[ti][0][r] * 10.0f : -1e30f;
      const float s1 = (gc1 < L) ? acc[ti][1][r] * 10.0f : -1e30f;
      float m = fmaxf(s0, s1);
#pragma unroll
      for (int d = 1; d < 16; d <<= 1) m = fmaxf(m, __shfl_xor(m, d, 64));
      float den = 0.f, msum = 0.f, cnt = 0.f, badf = 0.f;
      if (gc0 < L) {
        if (gc0 != grow) { den += __expf(s0 - m); msum += mk0 * s0; cnt += mk0; }
        const float sane = (gc0 == grow && grow != 0) ? 1.f : 0.f;
        badf = fmaxf(badf, (mk0 != sane) ? 1.f : 0.f);
      }
      if (gc1 < L) {
        if (gc1 != grow) { den += __expf(s1 - m); msum += mk1 * s1; cnt += mk1; }
        const float sane = (gc1 == grow && grow != 0) ? 1.f : 0.f;
        badf = fmaxf(badf, (mk1 != sane) ? 1.f : 0.f);
      }
#pragma unroll
      for (int d = 1; d < 16; d <<= 1) {
        den  += __shfl_xor(den, d, 64);
        msum += __shfl_xor(msum, d, 64);
        cnt  += __shfl_xor(cnt, d, 64);
        badf  = fmaxf(badf, __shfl_xor(badf, d, 64));
      }
      if (fr == 0) {
        const int slot = wave & 3;
        rp_m[lrow * 4 + slot] = m;   rp_d[lrow * 4 + slot] = den;
        rp_s[lrow * 4 + slot] = msum; rp_c[lrow * 4 + slot] = cnt;
        rp_b[lrow * 4 + slot] = badf;
      }
    }
  }
  __syncthreads();

  if (tid < 128) {
    float m = -1e30f;
#pragma unroll
    for (int s = 0; s < 4; s++) m = fmaxf(m, rp_m[tid * 4 + s]);
    float den = 0.f, msum = 0.f, cnt = 0.f, badf = 0.f;
#pragma unroll
    for (int s = 0; s < 4; s++) {
      den  += rp_d[tid * 4 + s] * __expf(rp_m[tid * 4 + s] - m);   // empty: 0*0
      msum += rp_s[tid * 4 + s];
      cnt  += rp_c[tid * 4 + s];
      badf  = fmaxf(badf, rp_b[tid * 4 + s]);
    }
    float* p = part + ((((size_t)b * 1024 + row0 + tid) * 8) + ct) * 5;
    p[0] = m; p[1] = den; p[2] = msum; p[3] = cnt; p[4] = badf;
  }
}

// ---------------- reduce: merge 8 column-tile slots per row ----------------
__global__ __launch_bounds__(256) void reduce_kernel(const float* __restrict__ part,
                                                     const int* __restrict__ icl,
                                                     float* __restrict__ blk_sum,
                                                     int* __restrict__ blk_bad) {
  const int blk = blockIdx.x;
  const int row = blk * 256 + threadIdx.x;   // 0..8191
  const int b = row >> 10;
  const int i = row & 1023;
  const int L = icl[b] + 1;
  float rv = 0.f;
  int bad = 0;
  if (i < L) {
    const float* p = part + (size_t)row * 40;
    const int ns = (L + 127) >> 7;           // valid slots
    float m = -1e30f;
    for (int s = 0; s < ns; s++) m = fmaxf(m, p[s * 5 + 0]);
    float den = 0.f, msum = 0.f, cnt = 0.f, badf = 0.f;
    for (int s = 0; s < ns; s++) {
      den  += p[s * 5 + 1] * __expf(p[s * 5 + 0] - m);
      msum += p[s * 5 + 2];
      cnt  += p[s * 5 + 3];
      badf  = fmaxf(badf, p[s * 5 + 4]);
    }
    const float A = msum - cnt * m;          // sum mask*(s - mx)
    const float mlpp = (A - cnt * __logf(den + 1e-6f)) / (cnt + 1e-6f);
    rv = -mlpp / (float)L;
    bad = badf > 0.f ? 1 : 0;
  }
  const int tid  = threadIdx.x;
  const int lane = tid & 63;
  const int wave = tid >> 6;
  for (int o = 32; o > 0; o >>= 1) rv += __shfl_down(rv, o, 64);
  const int wbad = (__ballot(bad) != 0ull) ? 1 : 0;
  __shared__ float sred[4];
  __shared__ int bred[4];
  if (lane == 0) { sred[wave] = rv; bred[wave] = wbad; }
  __syncthreads();
  if (tid == 0) {
    blk_sum[blk] = sred[0] + sred[1] + sred[2] + sred[3];
    blk_bad[blk] = bred[0] | bred[1] | bred[2] | bred[3];
  }
}

// ---------------- finalize (single wave, deterministic) ----------------
__global__ __launch_bounds__(64) void final_kernel(const float* __restrict__ blk_sum,
                                                   const int* __restrict__ blk_bad,
                                                   float* __restrict__ out) {
  const int tid = threadIdx.x;
  float v = (tid < 32) ? blk_sum[tid] : 0.f;
  for (int o = 32; o > 0; o >>= 1) v += __shfl_down(v, o, 64);
  if (tid == 0) {
    int vcount = 0;
    for (int bb = 0; bb < B_DIM; bb++) {
      const int any = blk_bad[bb * 4] | blk_bad[bb * 4 + 1] |
                      blk_bad[bb * 4 + 2] | blk_bad[bb * 4 + 3];
      vcount += any ? 1 : 0;
    }
    out[0] = v / fmaxf((float)vcount, 1.0f);
  }
}

extern "C" void kernel_launch(void* const* d_in, const int* in_sizes, int n_in,
                              void* d_out, int out_size, void* d_ws, size_t ws_size,
                              hipStream_t stream) {
  const float* feat = (const float*)d_in[0];
  const float* mask = (const float*)d_in[1];
  const int*   icl  = (const int*)d_in[2];
  float* out = (float*)d_out;

  char* ws = (char*)d_ws;
  __hip_bfloat16* Fb = (__hip_bfloat16*)ws;                 // 16 MiB
  float* part    = (float*)(ws + (16u << 20));              // 1.31 MiB
  float* blk_sum = (float*)(ws + (18u << 20));              // 128 B
  int*   blk_bad = (int*)(ws + (18u << 20) + 512);          // 128 B

  convert_kernel<<<dim3(8192), dim3(256), 0, stream>>>(feat, Fb);
  fused_kernel<<<dim3(512), dim3(512), 0, stream>>>(Fb, mask, icl, part);
  reduce_kernel<<<dim3(32), dim3(256), 0, stream>>>(part, icl, blk_sum, blk_bad);
  final_kernel<<<dim3(1), dim3(64), 0, stream>>>(blk_sum, blk_bad, out);
}

// Round 3
// 120.350 us; speedup vs baseline: 1.1893x; 1.1893x over previous
//
#include <hip/hip_runtime.h>
#include <hip/hip_bf16.h>
#include <stdint.h>

#define T_DIM 1024
#define B_DIM 8

typedef __attribute__((ext_vector_type(8))) short short8;
typedef __attribute__((ext_vector_type(4))) float f32x4;

__device__ inline void gll16(const void* g, void* l) {
  __builtin_amdgcn_global_load_lds((__attribute__((address_space(1))) void*)g,
                                   (__attribute__((address_space(3))) void*)l,
                                   16, 0, 0);
}

// ---------------- fp32 -> bf16 convert ----------------
__global__ __launch_bounds__(256) void convert_kernel(const float* __restrict__ F,
                                                      __hip_bfloat16* __restrict__ Fb) {
  const int t = blockIdx.x * 256 + threadIdx.x;
  const float4 v = ((const float4*)F)[t];
  union { __hip_bfloat16 h[4]; uint64_t u; } p;
  p.h[0] = __float2bfloat16(v.x);
  p.h[1] = __float2bfloat16(v.y);
  p.h[2] = __float2bfloat16(v.z);
  p.h[3] = __float2bfloat16(v.w);
  ((uint64_t*)Fb)[t] = p.u;
}

// ---------------- fused Gram + row-partial kernel ----------------
// 512 threads = 8 waves (2x4 wave grid) on a 128x128 tile.
// Round-3 change: SWAPPED MFMA operands -> C/D transposed: lane fr = output
// ROW, regs (q,r) = output COLUMNS. Row-reduction (max/den/msum/cnt/bad) is
// now 8 in-register cols + 2 shuffles (xor 16,32) per quantity: 40 shuffles
// per wave instead of 320 (T12 mechanism: make the reduction axis lane-local).
// Mask loads become 8 float4 (consecutive cols per lane), issued at epilogue
// start -> not live across the K-loop -> no scratch spill (round-2's 9 MB
// WRITE_SIZE regression).
// K-loop: counted-vmcnt pipeline (T4) retained from round 2.
__global__ __launch_bounds__(512, 4) void fused_kernel(const __hip_bfloat16* __restrict__ Fb,
                                                       const float* __restrict__ M,
                                                       const int* __restrict__ icl,
                                                       float* __restrict__ part) {
  const int id = blockIdx.x;
  const int b  = id & 7;          // XCD = wgid % 8 -> all tiles of batch b on one XCD
  const int rt = (id >> 3) & 7;
  const int ct = id >> 6;
  const int L  = icl[b] + 1;
  if (rt * 128 >= L || ct * 128 >= L) return;   // tile fully invalid (uniform exit)

  __shared__ char smem[65536];
  __hip_bfloat16* As = (__hip_bfloat16*)smem;            // [2 buf][2 kk][128][32] = 32 KB
  __hip_bfloat16* Bs = (__hip_bfloat16*)(smem + 32768);  // 32 KB
  float* rp = (float*)smem;  // reused after K-loop: 5 arrays of 128x4 floats
  float* rp_m = rp;          // [row*4 + slot]
  float* rp_d = rp + 512;
  float* rp_s = rp + 1024;
  float* rp_c = rp + 1536;
  float* rp_b = rp + 2048;

  const __hip_bfloat16* F = Fb + ((size_t)b << 20);
  const int tid  = threadIdx.x;
  const int lane = tid & 63;
  const int wave = tid >> 6;            // 0..7
  const int wrow = (wave >> 2) * 64;    // 0 / 64
  const int wcol = (wave & 3) * 32;     // 0 / 32 / 64 / 96
  const int row0 = rt * 128;
  const int col0 = ct * 128;

  const int fr = lane & 15;             // fragment index within 16
  const int q  = lane >> 4;             // quarter-wave (k-granule)
  const int sl8 = (q ^ ((fr >> 1) & 3)) * 8;   // swizzled slot (elements)

  // staging: thread l -> LDS row l>>2, slot l&3; source granule = swizzle^-1
  const int srow = tid >> 2;                                  // 0..127
  const int sgk  = (((tid & 3) ^ ((tid >> 3) & 3)) * 8);      // source k offset

  const size_t arow = (size_t)(row0 + srow) * T_DIM + sgk;
  const size_t brow = (size_t)(col0 + srow) * T_DIM + sgk;

  auto stage = [&](int buf, int step) {
    const int kb = step << 6;     // BK = 64
#pragma unroll
    for (int p = 0; p < 2; p++)
      gll16(F + arow + kb + p * 32, As + buf * 8192 + p * 4096 + tid * 8);
#pragma unroll
    for (int p = 0; p < 2; p++)
      gll16(F + brow + kb + p * 32, Bs + buf * 8192 + p * 4096 + tid * 8);
  };

  // prologue: two tiles in flight (8 gll16)
  stage(0, 0);
  stage(1, 1);

  f32x4 acc[4][2];
#pragma unroll
  for (int i = 0; i < 4; i++)
#pragma unroll
    for (int j = 0; j < 2; j++) acc[i][j] = (f32x4){0.f, 0.f, 0.f, 0.f};

#pragma unroll
  for (int t = 0; t < 16; ++t) {
    const int cur = t & 1;
    // own tile-t loads landed; tile-(t+1) loads (4) stay in flight
    if (t < 15) { asm volatile("s_waitcnt vmcnt(4)" ::: "memory"); }
    else        { asm volatile("s_waitcnt vmcnt(0)" ::: "memory"); }
    __builtin_amdgcn_s_barrier();                 // (A) tile t visible everywhere
    __builtin_amdgcn_sched_barrier(0);

    short8 af[2][4], bfr[2][2];
    const __hip_bfloat16* Ab = As + cur * 8192;
    const __hip_bfloat16* Bb = Bs + cur * 8192;
#pragma unroll
    for (int kk = 0; kk < 2; kk++) {
#pragma unroll
      for (int tt = 0; tt < 4; tt++)
        af[kk][tt] = *(const short8*)(Ab + kk * 4096 + (wrow + tt * 16 + fr) * 32 + sl8);
#pragma unroll
      for (int j = 0; j < 2; j++)
        bfr[kk][j] = *(const short8*)(Bb + kk * 4096 + (wcol + j * 16 + fr) * 32 + sl8);
    }
    asm volatile("s_waitcnt lgkmcnt(0)" ::: "memory");
    __builtin_amdgcn_sched_barrier(0);
    __builtin_amdgcn_s_barrier();                 // (B) all reads done -> buf free
    __builtin_amdgcn_sched_barrier(0);

    if (t < 14) stage(cur, t + 2);                // refill freed buffer

    // SWAPPED operand order: A-operand = bfr (cols), B-operand = af (rows)
    // -> D[row-in-lane(fr) = global row, col-in-regs(q,r) = global col]
    __builtin_amdgcn_s_setprio(1);
#pragma unroll
    for (int kk = 0; kk < 2; kk++)
#pragma unroll
      for (int ti = 0; ti < 4; ti++)
#pragma unroll
        for (int tj = 0; tj < 2; tj++)
          acc[ti][tj] = __builtin_amdgcn_mfma_f32_16x16x32_bf16(bfr[kk][tj], af[kk][ti], acc[ti][tj], 0, 0, 0);
    __builtin_amdgcn_s_setprio(0);
  }
  __syncthreads();   // all frag reads done before rp aliases the staging LDS

  // ---- epilogue (transposed C/D) ----
  // acc[ti][tj][r]: row = row0 + wrow + ti*16 + fr ; col = col0 + wcol + tj*16 + q*4 + r
  // mask loads: 8 float4, consecutive cols per lane, always in-bounds
  uint32_t mbits = 0;   // bit = ti*8 + tj*4 + r
  {
    const float* Mb = M + ((size_t)b << 20);
    union { float4 v; float f[4]; } mv[4][2];
#pragma unroll
    for (int ti = 0; ti < 4; ti++) {
      const int grow = row0 + wrow + ti * 16 + fr;
#pragma unroll
      for (int tj = 0; tj < 2; tj++)
        mv[ti][tj].v = *(const float4*)(Mb + ((size_t)grow << 10) + col0 + wcol + tj * 16 + q * 4);
    }
#pragma unroll
    for (int ti = 0; ti < 4; ti++)
#pragma unroll
      for (int tj = 0; tj < 2; tj++)
#pragma unroll
        for (int r = 0; r < 4; r++)
          mbits |= ((mv[ti][tj].f[r] != 0.f) ? 1u : 0u) << (ti * 8 + tj * 4 + r);
  }

#pragma unroll
  for (int ti = 0; ti < 4; ti++) {
    const int lrow = wrow + ti * 16 + fr;    // 0..127
    const int grow = row0 + lrow;
    float s[2][4];
#pragma unroll
    for (int tj = 0; tj < 2; tj++)
#pragma unroll
      for (int r = 0; r < 4; r++) {
        const int gcol = col0 + wcol + tj * 16 + q * 4 + r;
        s[tj][r] = (gcol < L) ? acc[ti][tj][r] * 10.0f : -1e30f;
      }
    float m = s[0][0];
#pragma unroll
    for (int tj = 0; tj < 2; tj++)
#pragma unroll
      for (int r = 0; r < 4; r++) m = fmaxf(m, s[tj][r]);
    m = fmaxf(m, __shfl_xor(m, 16, 64));
    m = fmaxf(m, __shfl_xor(m, 32, 64));

    float den = 0.f, msum = 0.f, cnt = 0.f, badf = 0.f;
#pragma unroll
    for (int tj = 0; tj < 2; tj++)
#pragma unroll
      for (int r = 0; r < 4; r++) {
        const int gcol = col0 + wcol + tj * 16 + q * 4 + r;
        if (gcol < L) {
          const float mk = (float)((mbits >> (ti * 8 + tj * 4 + r)) & 1u);
          if (gcol != grow) {
            den  += __expf(s[tj][r] - m);
            msum += mk * s[tj][r];
            cnt  += mk;
          }
          const float sane = (gcol == grow && grow != 0) ? 1.f : 0.f;
          badf = fmaxf(badf, (mk != sane) ? 1.f : 0.f);
        }
      }
    den  += __shfl_xor(den, 16, 64);  den  += __shfl_xor(den, 32, 64);
    msum += __shfl_xor(msum, 16, 64); msum += __shfl_xor(msum, 32, 64);
    cnt  += __shfl_xor(cnt, 16, 64);  cnt  += __shfl_xor(cnt, 32, 64);
    badf = fmaxf(badf, __shfl_xor(badf, 16, 64));
    badf = fmaxf(badf, __shfl_xor(badf, 32, 64));

    if (q == 0) {
      const int slot = wave & 3;
      rp_m[lrow * 4 + slot] = m;    rp_d[lrow * 4 + slot] = den;
      rp_s[lrow * 4 + slot] = msum; rp_c[lrow * 4 + slot] = cnt;
      rp_b[lrow * 4 + slot] = badf;
    }
  }
  __syncthreads();

  if (tid < 128) {
    float m = -1e30f;
#pragma unroll
    for (int s = 0; s < 4; s++) m = fmaxf(m, rp_m[tid * 4 + s]);
    float den = 0.f, msum = 0.f, cnt = 0.f, badf = 0.f;
#pragma unroll
    for (int s = 0; s < 4; s++) {
      den  += rp_d[tid * 4 + s] * __expf(rp_m[tid * 4 + s] - m);   // empty: 0*0
      msum += rp_s[tid * 4 + s];
      cnt  += rp_c[tid * 4 + s];
      badf  = fmaxf(badf, rp_b[tid * 4 + s]);
    }
    float* p = part + ((((size_t)b * 1024 + row0 + tid) * 8) + ct) * 5;
    p[0] = m; p[1] = den; p[2] = msum; p[3] = cnt; p[4] = badf;
  }
}

// ---------------- reduce: merge 8 column-tile slots per row ----------------
__global__ __launch_bounds__(256) void reduce_kernel(const float* __restrict__ part,
                                                     const int* __restrict__ icl,
                                                     float* __restrict__ blk_sum,
                                                     int* __restrict__ blk_bad) {
  const int blk = blockIdx.x;
  const int row = blk * 256 + threadIdx.x;   // 0..8191
  const int b = row >> 10;
  const int i = row & 1023;
  const int L = icl[b] + 1;
  float rv = 0.f;
  int bad = 0;
  if (i < L) {
    const float* p = part + (size_t)row * 40;
    const int ns = (L + 127) >> 7;           // valid slots
    float m = -1e30f;
    for (int s = 0; s < ns; s++) m = fmaxf(m, p[s * 5 + 0]);
    float den = 0.f, msum = 0.f, cnt = 0.f, badf = 0.f;
    for (int s = 0; s < ns; s++) {
      den  += p[s * 5 + 1] * __expf(p[s * 5 + 0] - m);
      msum += p[s * 5 + 2];
      cnt  += p[s * 5 + 3];
      badf  = fmaxf(badf, p[s * 5 + 4]);
    }
    const float A = msum - cnt * m;          // sum mask*(s - mx)
    const float mlpp = (A - cnt * __logf(den + 1e-6f)) / (cnt + 1e-6f);
    rv = -mlpp / (float)L;
    bad = badf > 0.f ? 1 : 0;
  }
  const int tid  = threadIdx.x;
  const int lane = tid & 63;
  const int wave = tid >> 6;
  for (int o = 32; o > 0; o >>= 1) rv += __shfl_down(rv, o, 64);
  const int wbad = (__ballot(bad) != 0ull) ? 1 : 0;
  __shared__ float sred[4];
  __shared__ int bred[4];
  if (lane == 0) { sred[wave] = rv; bred[wave] = wbad; }
  __syncthreads();
  if (tid == 0) {
    blk_sum[blk] = sred[0] + sred[1] + sred[2] + sred[3];
    blk_bad[blk] = bred[0] | bred[1] | bred[2] | bred[3];
  }
}

// ---------------- finalize (single wave, deterministic) ----------------
__global__ __launch_bounds__(64) void final_kernel(const float* __restrict__ blk_sum,
                                                   const int* __restrict__ blk_bad,
                                                   float* __restrict__ out) {
  const int tid = threadIdx.x;
  float v = (tid < 32) ? blk_sum[tid] : 0.f;
  for (int o = 32; o > 0; o >>= 1) v += __shfl_down(v, o, 64);
  if (tid == 0) {
    int vcount = 0;
    for (int bb = 0; bb < B_DIM; bb++) {
      const int any = blk_bad[bb * 4] | blk_bad[bb * 4 + 1] |
                      blk_bad[bb * 4 + 2] | blk_bad[bb * 4 + 3];
      vcount += any ? 1 : 0;
    }
    out[0] = v / fmaxf((float)vcount, 1.0f);
  }
}

extern "C" void kernel_launch(void* const* d_in, const int* in_sizes, int n_in,
                              void* d_out, int out_size, void* d_ws, size_t ws_size,
                              hipStream_t stream) {
  const float* feat = (const float*)d_in[0];
  const float* mask = (const float*)d_in[1];
  const int*   icl  = (const int*)d_in[2];
  float* out = (float*)d_out;

  char* ws = (char*)d_ws;
  __hip_bfloat16* Fb = (__hip_bfloat16*)ws;                 // 16 MiB
  float* part    = (float*)(ws + (16u << 20));              // 1.31 MiB
  float* blk_sum = (float*)(ws + (18u << 20));              // 128 B
  int*   blk_bad = (int*)(ws + (18u << 20) + 512);          // 128 B

  convert_kernel<<<dim3(8192), dim3(256), 0, stream>>>(feat, Fb);
  fused_kernel<<<dim3(512), dim3(512), 0, stream>>>(Fb, mask, icl, part);
  reduce_kernel<<<dim3(32), dim3(256), 0, stream>>>(part, icl, blk_sum, blk_bad);
  final_kernel<<<dim3(1), dim3(64), 0, stream>>>(blk_sum, blk_bad, out);
}